// Round 5
// baseline (76.721 us; speedup 1.0000x reference)
//
#include <hip/hip_runtime.h>
#include <hip/hip_bf16.h>

#define IMG_H 512
#define IMG_W 512
#define NBLOCKS 1536
#define TOTAL_ELEMS (48LL * 512 * 512)   // 16*3*512*512

__device__ __forceinline__ float fast_sqrtf(float x) {
    float r; asm("v_sqrt_f32 %0, %1" : "=v"(r) : "v"(x)); return r;   // ~1 ulp
}

__device__ __forceinline__ void load8(const float* __restrict__ p, float v[8]) {
    const float4 x = *reinterpret_cast<const float4*>(p);
    const float4 y = *reinterpret_cast<const float4*>(p + 4);
    v[0] = x.x; v[1] = x.y; v[2] = x.z; v[3] = x.w;
    v[4] = y.x; v[5] = y.y; v[6] = y.z; v[7] = y.w;
}

__device__ __forceinline__ void lds_read8(const float* __restrict__ s, float v[8]) {
    const float4 x = *reinterpret_cast<const float4*>(s);
    const float4 y = *reinterpret_cast<const float4*>(s + 4);
    v[0] = x.x; v[1] = x.y; v[2] = x.z; v[3] = x.w;
    v[4] = y.x; v[5] = y.y; v[6] = y.z; v[7] = y.w;
}

// Both images' Sobel magnitudes for one output row + |diff| partial sum.
// Column halo via shuffles on the linear vertical-pass terms (zero pad at edges).
__device__ __forceinline__ float row_absdiff(const float t1[8], const float m1[8], const float b1[8],
                                             const float t2[8], const float m2[8], const float b2[8],
                                             int lane) {
    float cs1[8], rd1[8], cs2[8], rd2[8];
#pragma unroll
    for (int j = 0; j < 8; ++j) {
        cs1[j] = (t1[j] + b1[j]) + 2.0f * m1[j];
        rd1[j] = b1[j] - t1[j];
        cs2[j] = (t2[j] + b2[j]) + 2.0f * m2[j];
        rd2[j] = b2[j] - t2[j];
    }
    float cs1L = __shfl_up(cs1[7], 1), cs1R = __shfl_down(cs1[0], 1);
    float rd1L = __shfl_up(rd1[7], 1), rd1R = __shfl_down(rd1[0], 1);
    float cs2L = __shfl_up(cs2[7], 1), cs2R = __shfl_down(cs2[0], 1);
    float rd2L = __shfl_up(rd2[7], 1), rd2R = __shfl_down(rd2[0], 1);
    if (lane == 0)  { cs1L = rd1L = cs2L = rd2L = 0.0f; }
    if (lane == 63) { cs1R = rd1R = cs2R = rd2R = 0.0f; }
    float s = 0.0f;
#pragma unroll
    for (int j = 0; j < 8; ++j) {
        const float ex1 = ((j == 7) ? cs1R : cs1[j + 1]) - ((j == 0) ? cs1L : cs1[j - 1]);
        const float ey1 = ((j == 0) ? rd1L : rd1[j - 1]) + 2.0f * rd1[j] + ((j == 7) ? rd1R : rd1[j + 1]);
        const float mg1 = fast_sqrtf(fmaf(ex1, ex1, fmaf(ey1, ey1, 1e-6f)));
        const float ex2 = ((j == 7) ? cs2R : cs2[j + 1]) - ((j == 0) ? cs2L : cs2[j - 1]);
        const float ey2 = ((j == 0) ? rd2L : rd2[j - 1]) + 2.0f * rd2[j] + ((j == 7) ? rd2R : rd2[j + 1]);
        const float mg2 = fast_sqrtf(fmaf(ex2, ex2, fmaf(ey2, ey2, 1e-6f)));
        s += fabsf(mg1 - mg2);
    }
    return s;
}

// Block = 4 waves = 16-row x 512-col tile. Each wave loads only its 4 rows
// (+1 global halo row for waves 0/3); wave-boundary rows via LDS (1.125x reads).
// Finalize fused via last-block ticket. Grid 1536 = 8 XCDs * 192, swizzled.
__global__ __launch_bounds__(256, 4) void edge_loss_kernel(const float* __restrict__ img1,
                                                           const float* __restrict__ img2,
                                                           float* __restrict__ slots,
                                                           unsigned* __restrict__ ticket,
                                                           float* __restrict__ out) {
    const int t = threadIdx.x;
    const int lane = t & 63;
    const int w = t >> 6;
    const int bid = blockIdx.x;
    const int swz = (bid & 7) * 192 + (bid >> 3);    // bijective XCD swizzle
    const int plane = swz >> 5;                      // 32 blocks per plane
    const int blk = swz & 31;
    const int yb = blk << 4;
    const int y0 = yb + (w << 2);
    const int x0 = lane << 3;
    const size_t base = (size_t)plane * (IMG_H * IMG_W);
    const float* p1 = img1 + base + x0;
    const float* p2 = img2 + base + x0;

    __shared__ float sh[2][4][2][IMG_W];             // 32 KB halo-exchange
    __shared__ float wave_sums[4];
    __shared__ bool amLast;

    float a[4][8], b[4][8];
#pragma unroll
    for (int r = 0; r < 4; ++r) {
        load8(p1 + (size_t)(y0 + r) * IMG_W, a[r]);
        load8(p2 + (size_t)(y0 + r) * IMG_W, b[r]);
    }

    float ha[8], hb[8];
    bool hzero = false;
    if (w == 0) {
        hzero = (yb == 0);
        const int y = hzero ? 0 : yb - 1;
        load8(p1 + (size_t)y * IMG_W, ha);
        load8(p2 + (size_t)y * IMG_W, hb);
    } else if (w == 3) {
        hzero = (yb + 16 == IMG_H);
        const int y = hzero ? IMG_H - 1 : yb + 16;
        load8(p1 + (size_t)y * IMG_W, ha);
        load8(p2 + (size_t)y * IMG_W, hb);
    }
    if ((w == 0 || w == 3) && hzero) {
#pragma unroll
        for (int j = 0; j < 8; ++j) { ha[j] = 0.0f; hb[j] = 0.0f; }
    }

    *reinterpret_cast<float4*>(&sh[0][w][0][x0])     = make_float4(a[0][0], a[0][1], a[0][2], a[0][3]);
    *reinterpret_cast<float4*>(&sh[0][w][0][x0 + 4]) = make_float4(a[0][4], a[0][5], a[0][6], a[0][7]);
    *reinterpret_cast<float4*>(&sh[0][w][1][x0])     = make_float4(a[3][0], a[3][1], a[3][2], a[3][3]);
    *reinterpret_cast<float4*>(&sh[0][w][1][x0 + 4]) = make_float4(a[3][4], a[3][5], a[3][6], a[3][7]);
    *reinterpret_cast<float4*>(&sh[1][w][0][x0])     = make_float4(b[0][0], b[0][1], b[0][2], b[0][3]);
    *reinterpret_cast<float4*>(&sh[1][w][0][x0 + 4]) = make_float4(b[0][4], b[0][5], b[0][6], b[0][7]);
    *reinterpret_cast<float4*>(&sh[1][w][1][x0])     = make_float4(b[3][0], b[3][1], b[3][2], b[3][3]);
    *reinterpret_cast<float4*>(&sh[1][w][1][x0 + 4]) = make_float4(b[3][4], b[3][5], b[3][6], b[3][7]);
    __syncthreads();

    float sum = 0.0f;
    {   // output row 0 (top halo read just-in-time)
        float ta[8], tb[8];
        if (w == 0) {
#pragma unroll
            for (int j = 0; j < 8; ++j) { ta[j] = ha[j]; tb[j] = hb[j]; }
        } else {
            lds_read8(&sh[0][w - 1][1][x0], ta);
            lds_read8(&sh[1][w - 1][1][x0], tb);
        }
        sum += row_absdiff(ta, a[0], a[1], tb, b[0], b[1], lane);
    }
    sum += row_absdiff(a[0], a[1], a[2], b[0], b[1], b[2], lane);
    sum += row_absdiff(a[1], a[2], a[3], b[1], b[2], b[3], lane);
    {   // output row 3 (bottom halo read just-in-time)
        float ba[8], bb[8];
        if (w == 3) {
#pragma unroll
            for (int j = 0; j < 8; ++j) { ba[j] = ha[j]; bb[j] = hb[j]; }
        } else {
            lds_read8(&sh[0][w + 1][0][x0], ba);
            lds_read8(&sh[1][w + 1][0][x0], bb);
        }
        sum += row_absdiff(a[2], a[3], ba, b[2], b[3], bb, lane);
    }

#pragma unroll
    for (int off = 32; off > 0; off >>= 1) sum += __shfl_down(sum, off);
    if (lane == 0) wave_sums[w] = sum;
    __syncthreads();

    if (t == 0) {
        const float s = (wave_sums[0] + wave_sums[1]) + (wave_sums[2] + wave_sums[3]);
        __hip_atomic_store(&slots[bid], s, __ATOMIC_RELAXED, __HIP_MEMORY_SCOPE_AGENT);
        __threadfence();
        const unsigned n = atomicAdd(ticket, 1u);    // device-scope
        amLast = (n == NBLOCKS - 1);
    }
    __syncthreads();                                  // amLast is block-uniform

    if (amLast) {                                     // unique last block finalizes
        __threadfence();
        float s = 0.0f;
#pragma unroll
        for (int i = 0; i < NBLOCKS / 256; ++i)       // fixed order -> deterministic
            s += __hip_atomic_load(&slots[t + i * 256], __ATOMIC_RELAXED, __HIP_MEMORY_SCOPE_AGENT);
#pragma unroll
        for (int off = 32; off > 0; off >>= 1) s += __shfl_down(s, off);
        if (lane == 0) wave_sums[w] = s;
        __syncthreads();
        if (t == 0) {
            out[0] = ((wave_sums[0] + wave_sums[1]) + (wave_sums[2] + wave_sums[3]))
                     * (1.0f / (float)TOTAL_ELEMS);
        }
    }
}

extern "C" void kernel_launch(void* const* d_in, const int* in_sizes, int n_in,
                              void* d_out, int out_size, void* d_ws, size_t ws_size,
                              hipStream_t stream) {
    const float* img1 = (const float*)d_in[0];
    const float* img2 = (const float*)d_in[1];
    float* out = (float*)d_out;
    unsigned* ticket = (unsigned*)d_ws;
    float* slots = (float*)((char*)d_ws + 256);

    hipMemsetAsync(ticket, 0, sizeof(unsigned), stream);
    edge_loss_kernel<<<dim3(NBLOCKS), 256, 0, stream>>>(img1, img2, slots, ticket, out);
}

// Round 6
// 69.497 us; speedup vs baseline: 1.1039x; 1.1039x over previous
//
#include <hip/hip_runtime.h>
#include <hip/hip_bf16.h>

#define IMG_H 512
#define IMG_W 512
#define NBLOCKS 1536
#define TOTAL_ELEMS (48LL * 512 * 512)   // 16*3*512*512

__device__ __forceinline__ float fast_sqrtf(float x) {
    float r; asm("v_sqrt_f32 %0, %1" : "=v"(r) : "v"(x)); return r;   // ~1 ulp
}

__device__ __forceinline__ void load8(const float* __restrict__ p, float v[8]) {
    const float4 x = *reinterpret_cast<const float4*>(p);
    const float4 y = *reinterpret_cast<const float4*>(p + 4);
    v[0] = x.x; v[1] = x.y; v[2] = x.z; v[3] = x.w;
    v[4] = y.x; v[5] = y.y; v[6] = y.z; v[7] = y.w;
}

__device__ __forceinline__ void lds_read8(const float* s, float v[8]) {
    const float4 x = *reinterpret_cast<const float4*>(s);
    const float4 y = *reinterpret_cast<const float4*>(s + 4);
    v[0] = x.x; v[1] = x.y; v[2] = x.z; v[3] = x.w;
    v[4] = y.x; v[5] = y.y; v[6] = y.z; v[7] = y.w;
}

__device__ __forceinline__ void lds_write8(float* s, const float v[8]) {
    *reinterpret_cast<float4*>(s)     = make_float4(v[0], v[1], v[2], v[3]);
    *reinterpret_cast<float4*>(s + 4) = make_float4(v[4], v[5], v[6], v[7]);
}

// Both images' Sobel magnitudes for one output row + |diff| partial sum.
// Column halo via shuffles on the linear vertical-pass terms (zero pad at edges).
__device__ __forceinline__ float row_absdiff(const float t1[8], const float m1[8], const float b1[8],
                                             const float t2[8], const float m2[8], const float b2[8],
                                             int lane) {
    float cs1[8], rd1[8], cs2[8], rd2[8];
#pragma unroll
    for (int j = 0; j < 8; ++j) {
        cs1[j] = (t1[j] + b1[j]) + 2.0f * m1[j];
        rd1[j] = b1[j] - t1[j];
        cs2[j] = (t2[j] + b2[j]) + 2.0f * m2[j];
        rd2[j] = b2[j] - t2[j];
    }
    float cs1L = __shfl_up(cs1[7], 1), cs1R = __shfl_down(cs1[0], 1);
    float rd1L = __shfl_up(rd1[7], 1), rd1R = __shfl_down(rd1[0], 1);
    float cs2L = __shfl_up(cs2[7], 1), cs2R = __shfl_down(cs2[0], 1);
    float rd2L = __shfl_up(rd2[7], 1), rd2R = __shfl_down(rd2[0], 1);
    if (lane == 0)  { cs1L = rd1L = cs2L = rd2L = 0.0f; }
    if (lane == 63) { cs1R = rd1R = cs2R = rd2R = 0.0f; }
    float s = 0.0f;
#pragma unroll
    for (int j = 0; j < 8; ++j) {
        const float ex1 = ((j == 7) ? cs1R : cs1[j + 1]) - ((j == 0) ? cs1L : cs1[j - 1]);
        const float ey1 = ((j == 0) ? rd1L : rd1[j - 1]) + 2.0f * rd1[j] + ((j == 7) ? rd1R : rd1[j + 1]);
        const float mg1 = fast_sqrtf(fmaf(ex1, ex1, fmaf(ey1, ey1, 1e-6f)));
        const float ex2 = ((j == 7) ? cs2R : cs2[j + 1]) - ((j == 0) ? cs2L : cs2[j - 1]);
        const float ey2 = ((j == 0) ? rd2L : rd2[j - 1]) + 2.0f * rd2[j] + ((j == 7) ? rd2R : rd2[j + 1]);
        const float mg2 = fast_sqrtf(fmaf(ex2, ex2, fmaf(ey2, ey2, 1e-6f)));
        s += fabsf(mg1 - mg2);
    }
    return s;
}

// Block = 4 waves = 16-row x 512-col tile. Each wave loads only its 4 rows;
// all halo rows (wave-boundary AND the 2 global ones) go through LDS, so no
// halo registers stay live during compute. Read amplification 1.125x.
// Finalize fused via last-block ticket. Grid 1536 = 8 XCDs * 192, swizzled.
// NOTE: no min-occupancy in launch_bounds — (256,4) forced VGPR=64 + spills (R5).
__global__ __launch_bounds__(256) void edge_loss_kernel(const float* __restrict__ img1,
                                                        const float* __restrict__ img2,
                                                        float* __restrict__ slots,
                                                        unsigned* __restrict__ ticket,
                                                        float* __restrict__ out) {
    const int t = threadIdx.x;
    const int lane = t & 63;
    const int w = t >> 6;
    const int bid = blockIdx.x;
    const int swz = (bid & 7) * 192 + (bid >> 3);    // bijective XCD swizzle
    const int plane = swz >> 5;                      // 32 blocks per plane
    const int blk = swz & 31;
    const int yb = blk << 4;
    const int y0 = yb + (w << 2);
    const int x0 = lane << 3;
    const size_t base = (size_t)plane * (IMG_H * IMG_W);
    const float* p1 = img1 + base + x0;
    const float* p2 = img2 + base + x0;

    // rows 0..7: wave w's first row at 2w, last row at 2w+1; 8 = global top halo,
    // 9 = global bottom halo. 40 KB.
    __shared__ float sh[2][10][IMG_W];
    __shared__ float wave_sums[4];
    __shared__ bool amLast;

    float a[4][8], b[4][8];
#pragma unroll
    for (int r = 0; r < 4; ++r) {
        load8(p1 + (size_t)(y0 + r) * IMG_W, a[r]);
        load8(p2 + (size_t)(y0 + r) * IMG_W, b[r]);
    }

    // global halo rows -> LDS (registers die right here)
    if (w == 0) {
        if (yb == 0) {
            const float4 z = make_float4(0.f, 0.f, 0.f, 0.f);
            *reinterpret_cast<float4*>(&sh[0][8][x0]) = z; *reinterpret_cast<float4*>(&sh[0][8][x0 + 4]) = z;
            *reinterpret_cast<float4*>(&sh[1][8][x0]) = z; *reinterpret_cast<float4*>(&sh[1][8][x0 + 4]) = z;
        } else {
            float h[8];
            load8(p1 + (size_t)(yb - 1) * IMG_W, h); lds_write8(&sh[0][8][x0], h);
            load8(p2 + (size_t)(yb - 1) * IMG_W, h); lds_write8(&sh[1][8][x0], h);
        }
    } else if (w == 3) {
        if (yb + 16 == IMG_H) {
            const float4 z = make_float4(0.f, 0.f, 0.f, 0.f);
            *reinterpret_cast<float4*>(&sh[0][9][x0]) = z; *reinterpret_cast<float4*>(&sh[0][9][x0 + 4]) = z;
            *reinterpret_cast<float4*>(&sh[1][9][x0]) = z; *reinterpret_cast<float4*>(&sh[1][9][x0 + 4]) = z;
        } else {
            float h[8];
            load8(p1 + (size_t)(yb + 16) * IMG_W, h); lds_write8(&sh[0][9][x0], h);
            load8(p2 + (size_t)(yb + 16) * IMG_W, h); lds_write8(&sh[1][9][x0], h);
        }
    }

    // publish own boundary rows
    lds_write8(&sh[0][2 * w][x0],     a[0]);
    lds_write8(&sh[0][2 * w + 1][x0], a[3]);
    lds_write8(&sh[1][2 * w][x0],     b[0]);
    lds_write8(&sh[1][2 * w + 1][x0], b[3]);
    __syncthreads();

    const int topIdx = (w == 0) ? 8 : 2 * w - 1;     // row y0-1
    const int botIdx = (w == 3) ? 9 : 2 * w + 2;     // row y0+4

    float sum = 0.0f;
    {   // output row 0 (top halo JIT from LDS)
        float ta[8], tb[8];
        lds_read8(&sh[0][topIdx][x0], ta);
        lds_read8(&sh[1][topIdx][x0], tb);
        sum += row_absdiff(ta, a[0], a[1], tb, b[0], b[1], lane);
    }
    sum += row_absdiff(a[0], a[1], a[2], b[0], b[1], b[2], lane);
    sum += row_absdiff(a[1], a[2], a[3], b[1], b[2], b[3], lane);
    {   // output row 3 (bottom halo JIT from LDS)
        float ba[8], bb[8];
        lds_read8(&sh[0][botIdx][x0], ba);
        lds_read8(&sh[1][botIdx][x0], bb);
        sum += row_absdiff(a[2], a[3], ba, b[2], b[3], bb, lane);
    }

#pragma unroll
    for (int off = 32; off > 0; off >>= 1) sum += __shfl_down(sum, off);
    if (lane == 0) wave_sums[w] = sum;
    __syncthreads();

    if (t == 0) {
        const float s = (wave_sums[0] + wave_sums[1]) + (wave_sums[2] + wave_sums[3]);
        __hip_atomic_store(&slots[bid], s, __ATOMIC_RELAXED, __HIP_MEMORY_SCOPE_AGENT);
        __threadfence();
        const unsigned n = atomicAdd(ticket, 1u);    // device-scope
        amLast = (n == NBLOCKS - 1);
    }
    __syncthreads();                                  // amLast is block-uniform

    if (amLast) {                                     // unique last block finalizes
        __threadfence();
        float s = 0.0f;
#pragma unroll
        for (int i = 0; i < NBLOCKS / 256; ++i)       // fixed order -> deterministic
            s += __hip_atomic_load(&slots[t + i * 256], __ATOMIC_RELAXED, __HIP_MEMORY_SCOPE_AGENT);
#pragma unroll
        for (int off = 32; off > 0; off >>= 1) s += __shfl_down(s, off);
        if (lane == 0) wave_sums[w] = s;
        __syncthreads();
        if (t == 0) {
            out[0] = ((wave_sums[0] + wave_sums[1]) + (wave_sums[2] + wave_sums[3]))
                     * (1.0f / (float)TOTAL_ELEMS);
        }
    }
}

extern "C" void kernel_launch(void* const* d_in, const int* in_sizes, int n_in,
                              void* d_out, int out_size, void* d_ws, size_t ws_size,
                              hipStream_t stream) {
    const float* img1 = (const float*)d_in[0];
    const float* img2 = (const float*)d_in[1];
    float* out = (float*)d_out;
    unsigned* ticket = (unsigned*)d_ws;
    float* slots = (float*)((char*)d_ws + 256);

    hipMemsetAsync(ticket, 0, sizeof(unsigned), stream);
    edge_loss_kernel<<<dim3(NBLOCKS), 256, 0, stream>>>(img1, img2, slots, ticket, out);
}